// Round 1
// baseline (290.231 us; speedup 1.0000x reference)
//
#include <hip/hip_runtime.h>
#include <math.h>

#define BB 128
#define QQ 900
#define GG 80
#define CC 92
#define NCL 91
#define NSLOT 15  // ceil(QQ/64)

#define NPART 8   // front: parts per batch (was 4)
#define QPB 128   // q rows per front block (8*128=1024 >= 900; part 7 has 4 rows)

// ---------------- ws layout (bytes) ---------------- (UNCHANGED vs prev round)
#define COST_OFF 0            // float[BB*GG*QQ]  36,864,000
#define LSE_OFF  36864000     // float[BB*QQ]
#define VIDX_OFF 37324800     // int[BB*GG]
#define NV_OFF   37365760     // int[BB]
#define FPART_OFF 37366272    // float[BB*NPART=1024] CE-base partials (same 4 KB region)
#define MPART_OFF 37370368    // double[BB*3] lsa matched partials [ce,l1,giou]

#define FRONT_LDS_BYTES (QPB * 93 * 4)   // 47,616 -> 3 blocks/CU (was 83,700 -> 1/CU)
#define NCACHE 44                         // lsa LDS row cache: 44*900*4 = 158,400 B
#define LSA_LDS_BYTES (NCACHE * QQ * 4)

// Fused front kernel v4: EIGHT blocks per batch (grid BB*8, 128 thr, 128 q each).
// Same staged-LDS structure as v3 (stride 93, conflict-free lane reads) but the
// slab shrinks 83.7KB -> 47.6KB so 3 blocks co-reside per CU (1.5 waves/SIMD vs
// 1.0) and the grid is 1024 blocks -- v3 was latency-bound at 1 wave/SIMD, ~9x
// over its memory roofline. All per-q fp32 expression trees are IDENTICAL to
// v3 -> cost/lse bits unchanged -> lsa traversal unchanged. CE-base partial is
// now a float per block (1024 floats fit the same 4 KB fpart region); rounding
// a ~650-magnitude partial to float perturbs out[0] by ~0.01 ulp.
__global__ __launch_bounds__(128) void front_kernel(const float* __restrict__ logits,
                                                    const float* __restrict__ pboxes,
                                                    const float* __restrict__ gboxes,
                                                    const int* __restrict__ glabels,
                                                    float* __restrict__ lse_g,
                                                    int* __restrict__ valid_idx,
                                                    int* __restrict__ nvalid,
                                                    float* __restrict__ cost,
                                                    float* __restrict__ fpart) {
    extern __shared__ float sL[];  // [QPB][93]
    __shared__ int svidx[GG];
    __shared__ int s_n;
    __shared__ int slab[GG];
    __shared__ float sgx0[GG], sgy0[GG], sgx1[GG], sgy1[GG], sgar[GG];
    __shared__ float sgcx[GG], sgcy[GG], sgcz[GG], sgcw[GG];
    __shared__ double sce[2];
    int blk = blockIdx.x;
    int b = blk >> 3;
    int part = blk & 7;
    int tid = threadIdx.x;
    int q0 = part * QPB;
    int qcnt = QQ - q0;
    if (qcnt > QPB) qcnt = QPB;
    if (tid < 64) {
        int lane = tid;
        bool v0 = glabels[b * GG + lane] < NCL;
        bool v1 = (lane < GG - 64) ? (glabels[b * GG + 64 + lane] < NCL) : false;
        unsigned long long m0 = __ballot(v0);
        unsigned long long m1 = __ballot(v1);
        int c0 = __popcll(m0);
        unsigned long long lower = lane ? (~0ULL >> (64 - lane)) : 0ULL;
        if (v0) { int p = __popcll(m0 & lower); svidx[p] = lane; valid_idx[b * GG + p] = lane; }
        if (v1) { int p = c0 + __popcll(m1 & lower); svidx[p] = 64 + lane; valid_idx[b * GG + p] = 64 + lane; }
        if (lane == 0) { s_n = c0 + __popcll(m1); nvalid[b] = s_n; }
    }
    __syncthreads();
    int n = s_n;

    // stage logits slab -> LDS (coalesced dword reads; padded stride 93)
    {
        const float* src = logits + ((size_t)b * QQ + q0) * CC;
        for (int i = tid; i < qcnt * CC; i += 128) {
            int ql = i / CC;
            int c = i - ql * CC;
            sL[ql * 93 + c] = src[i];
        }
    }
    // gt staging
    for (int k = tid; k < n; k += 128) {
        int g = svidx[k];
        slab[k] = glabels[b * GG + g];
        float4 gb = ((const float4*)gboxes)[b * GG + g];
        sgcx[k] = gb.x; sgcy[k] = gb.y; sgcz[k] = gb.z; sgcw[k] = gb.w;
        float gx0 = gb.x - 0.5f * gb.z, gy0 = gb.y - 0.5f * gb.w;
        float gx1 = gb.x + 0.5f * gb.z, gy1 = gb.y + 0.5f * gb.w;
        sgx0[k] = gx0; sgy0[k] = gy0; sgx1[k] = gx1; sgy1[k] = gy1;
        sgar[k] = (gx1 - gx0) * (gy1 - gy0);
    }
    __syncthreads();

    int q = q0 + tid;
    bool qok = tid < qcnt;
    const float* row = sL + tid * 93;

    // lse (identical expression tree; values from LDS are identical)
    double local = 0.0;
    float lse_q = 0.f;
    if (qok) {
        float mx = -INFINITY;
        for (int c = 0; c < 23; ++c) {
            float x0 = row[4 * c], x1 = row[4 * c + 1], x2 = row[4 * c + 2], x3 = row[4 * c + 3];
            mx = fmaxf(mx, fmaxf(fmaxf(x0, x1), fmaxf(x2, x3)));
        }
        float ssum = 0.f;
        float e91 = 0.f;
        for (int c = 0; c < 23; ++c) {
            float x0 = row[4 * c], x1 = row[4 * c + 1], x2 = row[4 * c + 2], x3 = row[4 * c + 3];
            ssum += expf(x0 - mx) + expf(x1 - mx) + expf(x2 - mx) + expf(x3 - mx);
            if (c == 22) e91 = x3;  // element 91
        }
        lse_q = mx + logf(ssum);
        lse_g[b * QQ + q] = lse_q;
        local = (double)lse_q - (double)e91;
    }
#pragma unroll
    for (int off = 32; off; off >>= 1) local += __shfl_down(local, off);
    if ((tid & 63) == 0) sce[tid >> 6] = local;

    // cost (identical fp32 op order; gather from LDS)
    if (qok) {
        float4 pb = ((const float4*)pboxes)[b * QQ + q];
        float px0 = pb.x - 0.5f * pb.z, py0 = pb.y - 0.5f * pb.w;
        float px1 = pb.x + 0.5f * pb.z, py1 = pb.y + 0.5f * pb.w;
        float parea = (px1 - px0) * (py1 - py0);
        for (int k = 0; k < n; ++k) {
            float l1 = fabsf(pb.x - sgcx[k]) + fabsf(pb.y - sgcy[k]) +
                       fabsf(pb.z - sgcz[k]) + fabsf(pb.w - sgcw[k]);
            float ltx = fmaxf(px0, sgx0[k]), lty = fmaxf(py0, sgy0[k]);
            float rbx = fminf(px1, sgx1[k]), rby = fminf(py1, sgy1[k]);
            float iw = fmaxf(rbx - ltx, 0.f), ih = fmaxf(rby - lty, 0.f);
            float inter = iw * ih;
            float uni = parea + sgar[k] - inter;
            float iou = inter / uni;
            float cx0 = fminf(px0, sgx0[k]), cy0 = fminf(py0, sgy0[k]);
            float cx1 = fmaxf(px1, sgx1[k]), cy1 = fmaxf(py1, sgy1[k]);
            float cw = fmaxf(cx1 - cx0, 0.f), ch = fmaxf(cy1 - cy0, 0.f);
            float ac = cw * ch;
            float giou = iou - (ac - uni) / ac;
            float cls = lse_q - row[slab[k]];
            cost[((size_t)(b * GG + k)) * QQ + q] = 5.f * l1 + cls - 2.f * giou;
        }
    }
    __syncthreads();
    if (tid == 0) fpart[blk] = (float)(sce[0] + sce[1]);
}

// Wave64 min-reduce via DPP (row_shr 1/2/4/8 + bcast15/31), result in lane 63.
__device__ __forceinline__ unsigned wave_min_u32(unsigned x) {
    unsigned t;
    t = (unsigned)__builtin_amdgcn_update_dpp((int)x, (int)x, 0x111, 0xF, 0xF, false); x = x < t ? x : t;
    t = (unsigned)__builtin_amdgcn_update_dpp((int)x, (int)x, 0x112, 0xF, 0xF, false); x = x < t ? x : t;
    t = (unsigned)__builtin_amdgcn_update_dpp((int)x, (int)x, 0x114, 0xF, 0xF, false); x = x < t ? x : t;
    t = (unsigned)__builtin_amdgcn_update_dpp((int)x, (int)x, 0x118, 0xF, 0xF, false); x = x < t ? x : t;
    t = (unsigned)__builtin_amdgcn_update_dpp((int)x, (int)x, 0x142, 0xF, 0xF, false); x = x < t ? x : t;
    t = (unsigned)__builtin_amdgcn_update_dpp((int)x, (int)x, 0x143, 0xF, 0xF, false); x = x < t ? x : t;
    return (unsigned)__builtin_amdgcn_readlane((int)x, 63);
}
// fp32 variant (fminf; values here are never NaN).
__device__ __forceinline__ float wave_min_f32(float x) {
    float t;
#define MSTEP(ctrl)                                                                               \
    t = __uint_as_float((unsigned)__builtin_amdgcn_update_dpp(                                    \
        (int)__float_as_uint(x), (int)__float_as_uint(x), ctrl, 0xF, 0xF, false));                \
    x = fminf(x, t);
    MSTEP(0x111) MSTEP(0x112) MSTEP(0x114) MSTEP(0x118) MSTEP(0x142) MSTEP(0x143)
#undef MSTEP
    return __uint_as_float((unsigned)__builtin_amdgcn_readlane((int)__float_as_uint(x), 63));
}

// One exact SAP phase (scipy semantics) for row `cur`.
// Bit-for-bit the R10-proven dataflow. The ONLY change: rows i2 < ncache are
// read from the LDS cost cache (a bit-exact copy of the same fp32 values) --
// ~93% of row reads drop from L2/L3 latency (~300-600 cy) to LDS (~120 cy).
__device__ __forceinline__ bool sap_phase(int cur, int lane, const float* cbase,
                                          const float* sC, int ncache,
                                          unsigned valid_mask, float (&v)[NSLOT],
                                          int (&r4c_r)[NSLOT], float (&u_r)[2],
                                          int (&c4r_r)[2]) {
    float sh[NSLOT];
    int path_r[NSLOT];
    float srv_r[2] = {0.f, 0.f};
    unsigned sc = 0, srm = 0;
#pragma unroll
    for (int s = 0; s < NSLOT; ++s) sh[s] = INFINITY;
    int i2 = cur;
    float minv = 0.f;
    int sink = -1;
    for (int pop = 0; pop < QQ && sink < 0; ++pop) {
        float uv = (i2 >> 6) ? u_r[1] : u_r[0];
        float ui = __uint_as_float(
            (unsigned)__builtin_amdgcn_readlane((int)__float_as_uint(uv), i2 & 63));
        float cv[NSLOT];
        if (i2 < ncache) {  // uniform (i2 is wave-uniform) -> scalar branch
            const float* srow = sC + i2 * QQ;
#pragma unroll
            for (int s = 0; s < NSLOT; ++s) {
                int j = s * 64 + lane;
                cv[s] = (j < QQ) ? srow[j] : 0.f;
            }
        } else {
            const float* crow = cbase + (size_t)i2 * QQ;
#pragma unroll
            for (int s = 0; s < NSLOT; ++s) {
                int j = s * 64 + lane;
                cv[s] = (j < QQ) ? crow[j] : 0.f;
            }
        }
        float base = minv - ui;
        unsigned act = valid_mask & ~sc;
        float lmin = INFINITY;
        int lslot = 0;
#pragma unroll
        for (int s = 0; s < NSLOT; ++s) {
            if ((act >> s) & 1u) {
                float r = base + cv[s] - v[s];
                if (r < sh[s]) { sh[s] = r; path_r[s] = i2; }
                if (sh[s] < lmin) { lmin = sh[s]; lslot = s; }
            }
        }
        float gmin = wave_min_f32(lmin);
        unsigned cand = (lmin == gmin) ? (unsigned)(lslot * 64 + lane) : 0xFFFFFFFFu;
        int lj = (int)wave_min_u32(cand);  // lowest column among ties
        minv = gmin;
        if (lane == (lj & 63)) sc |= (1u << (lj >> 6));
        int rv = -1;
#pragma unroll
        for (int s = 0; s < NSLOT; ++s)
            if (s == (lj >> 6)) rv = r4c_r[s];
        int r4c = __builtin_amdgcn_readlane(rv, lj & 63);
        if (r4c == -1) {
            sink = lj;
        } else {
            i2 = r4c;
            if (lane == (i2 & 63)) {
#pragma unroll
                for (int s = 0; s < 2; ++s)
                    if (s == (i2 >> 6)) { srm |= (1u << s); srv_r[s] = minv; }
            }
        }
    }
    if (sink < 0) return false;
    // dual updates (reference order: before augmentation)
    if (lane == (cur & 63)) {
#pragma unroll
        for (int s = 0; s < 2; ++s)
            if (s == (cur >> 6)) u_r[s] += minv;
    }
#pragma unroll
    for (int s = 0; s < 2; ++s)
        if ((srm >> s) & 1u) u_r[s] += minv - srv_r[s];
#pragma unroll
    for (int s = 0; s < NSLOT; ++s)
        if ((sc >> s) & 1u) v[s] -= (minv - sh[s]);
    // augment (wave-cooperative, uniform walk)
    int j = sink;
    while (true) {
        int pslot = j >> 6, plane = j & 63;
        int pv = 0;
#pragma unroll
        for (int s = 0; s < NSLOT; ++s)
            if (s == pslot) pv = path_r[s];
        int pi = __builtin_amdgcn_readlane(pv, plane);
        if (lane == plane) {
#pragma unroll
            for (int s = 0; s < NSLOT; ++s)
                if (s == pslot) r4c_r[s] = pi;
        }
        int cslot = pi >> 6, clane = pi & 63;
        int cvv = 0;
#pragma unroll
        for (int s = 0; s < 2; ++s)
            if (s == cslot) cvv = c4r_r[s];
        int nj = __builtin_amdgcn_readlane(cvv, clane);
        if (lane == clane) {
#pragma unroll
            for (int s = 0; s < 2; ++s)
                if (s == cslot) c4r_r[s] = j;
        }
        j = nj;
        if (pi == cur) break;
    }
    return true;
}

// R10-proven exact LSA + NEW: first min(n,44) cost rows cached in LDS (158.4 KB
// dynamic; the block is alone on its CU so the full 160 KiB is ours). Phase cur
// only visits rows <= cur, so the prefix cache captures ~93% of row reads.
// The cache is a bit-exact fp32 copy -> traversal identical -> matching identical.
__global__ __launch_bounds__(64, 1) void lsa_kernel(const float* __restrict__ cost,
                                                    const int* __restrict__ nvalid,
                                                    const int* __restrict__ valid_idx,
                                                    const int* __restrict__ glabels,
                                                    const float* __restrict__ lse_g,
                                                    const float* __restrict__ pboxes,
                                                    const float* __restrict__ gboxes,
                                                    const float* __restrict__ logits,
                                                    double* __restrict__ mpart) {
    extern __shared__ float sC[];  // [NCACHE][QQ]
    int b = blockIdx.x;
    int n = nvalid[b];
    const float* cbase = cost + (size_t)b * GG * QQ;
    int lane = threadIdx.x;

    // preload rows [0, ncache) -- bulk float4 copy, rows are contiguous
    int ncache = n < NCACHE ? n : NCACHE;
    {
        const float4* s4 = (const float4*)cbase;
        float4* d4 = (float4*)sC;
        int cnt = ncache * (QQ / 4);
        for (int i = lane; i < cnt; i += 64) d4[i] = s4[i];
    }
    __syncthreads();

    float v[NSLOT];
    int r4c_r[NSLOT];
    float u_r[2];
    int c4r_r[2];
    unsigned valid_mask = 0x3FFFu | ((lane < QQ - 14 * 64) ? 0x4000u : 0u);
#pragma unroll
    for (int s = 0; s < NSLOT; ++s) { v[s] = 0.f; r4c_r[s] = -1; }
#pragma unroll
    for (int s = 0; s < 2; ++s) { u_r[s] = 0.f; c4r_r[s] = -1; }

    for (int cur = 0; cur < n; ++cur)
        sap_phase(cur, lane, cbase, sC, ncache, valid_mask, v, r4c_r, u_r, c4r_r);

    // ---- fused matched-pair losses ----
    double ce = 0.0, dl1 = 0.0, dgi = 0.0;
#pragma unroll
    for (int s = 0; s < 2; ++s) {
        int r = s * 64 + lane;
        int q = c4r_r[s];
        if (r < n && q >= 0 && q < QQ) {
            int g = valid_idx[b * GG + r];
            int label = glabels[b * GG + g];
            if (label < 0 || label >= CC) label = 0;
            size_t ro = ((size_t)b * QQ + q) * CC;
            float ls = lse_g[b * QQ + q];
            float nll_lab = ls - logits[ro + label];
            float nll_no = ls - logits[ro + NCL];
            ce += 0.1 * (double)nll_lab - (double)nll_no;
            float4 pb = ((const float4*)pboxes)[b * QQ + q];
            float4 gb = ((const float4*)gboxes)[b * GG + g];
            float l1 = fabsf(pb.x - gb.x) + fabsf(pb.y - gb.y) + fabsf(pb.z - gb.z) + fabsf(pb.w - gb.w);
            float px0 = pb.x - 0.5f * pb.z, py0 = pb.y - 0.5f * pb.w;
            float px1 = pb.x + 0.5f * pb.z, py1 = pb.y + 0.5f * pb.w;
            float gx0 = gb.x - 0.5f * gb.z, gy0 = gb.y - 0.5f * gb.w;
            float gx1 = gb.x + 0.5f * gb.z, gy1 = gb.y + 0.5f * gb.w;
            float parea = (px1 - px0) * (py1 - py0);
            float garea = (gx1 - gx0) * (gy1 - gy0);
            float ltx = fmaxf(px0, gx0), lty = fmaxf(py0, gy0);
            float rbx = fminf(px1, gx1), rby = fminf(py1, gy1);
            float iw = fmaxf(rbx - ltx, 0.f), ih = fmaxf(rby - lty, 0.f);
            float inter = iw * ih;
            float uni = parea + garea - inter;
            float iou = inter / uni;
            float cx0 = fminf(px0, gx0), cy0 = fminf(py0, gy0);
            float cx1 = fmaxf(px1, gx1), cy1 = fmaxf(py1, gy1);
            float cw = fmaxf(cx1 - cx0, 0.f), ch = fmaxf(cy1 - cy0, 0.f);
            float ac = cw * ch;
            float giou = iou - (ac - uni) / ac;
            dl1 += (double)l1;
            dgi += 1.0 - (double)giou;
        }
    }
#pragma unroll
    for (int off = 32; off; off >>= 1) {
        ce += __shfl_down(ce, off);
        dl1 += __shfl_down(dl1, off);
        dgi += __shfl_down(dgi, off);
    }
    if (lane == 0) {
        mpart[b * 3 + 0] = ce;
        mpart[b * 3 + 1] = dl1;
        mpart[b * 3 + 2] = dgi;
    }
}

// One wave: sum partials + nvalid -> the three losses (no atomics anywhere).
__global__ __launch_bounds__(64) void final_kernel(const int* __restrict__ nvalid,
                                                   const float* __restrict__ fpart,
                                                   const double* __restrict__ mpart,
                                                   float* __restrict__ out) {
    int lane = threadIdx.x;
    int m = nvalid[lane] + nvalid[64 + lane];  // BB = 128
    double fb = 0.0;
    for (int i = lane; i < BB * NPART; i += 64) fb += (double)fpart[i];
    double ce = 0.0, dl1 = 0.0, dgi = 0.0;
#pragma unroll
    for (int s = 0; s < 2; ++s) {
        int bb = s * 64 + lane;
        ce += mpart[bb * 3 + 0];
        dl1 += mpart[bb * 3 + 1];
        dgi += mpart[bb * 3 + 2];
    }
#pragma unroll
    for (int off = 32; off; off >>= 1) {
        m += __shfl_down(m, off);
        fb += __shfl_down(fb, off);
        ce += __shfl_down(ce, off);
        dl1 += __shfl_down(dl1, off);
        dgi += __shfl_down(dgi, off);
    }
    if (lane == 0) {
        double M = (double)m;
        double sum_w = (double)(BB * QQ) - 0.9 * M;
        out[0] = (float)((fb + ce) / sum_w);
        out[1] = (float)(dl1 / (4.0 * M));
        out[2] = (float)(dgi / M);
    }
}

extern "C" void kernel_launch(void* const* d_in, const int* in_sizes, int n_in,
                              void* d_out, int out_size, void* d_ws, size_t ws_size,
                              hipStream_t stream) {
    const float* logits = (const float*)d_in[0];
    const float* pboxes = (const float*)d_in[1];
    const int* glabels = (const int*)d_in[2];
    const float* gboxes = (const float*)d_in[3];
    float* out = (float*)d_out;

    char* ws = (char*)d_ws;
    float* cost = (float*)(ws + COST_OFF);
    float* lse = (float*)(ws + LSE_OFF);
    int* vidx = (int*)(ws + VIDX_OFF);
    int* nval = (int*)(ws + NV_OFF);
    float* fpart = (float*)(ws + FPART_OFF);
    double* mpart = (double*)(ws + MPART_OFF);

    (void)hipFuncSetAttribute((const void*)front_kernel,
                              hipFuncAttributeMaxDynamicSharedMemorySize, FRONT_LDS_BYTES);
    (void)hipFuncSetAttribute((const void*)lsa_kernel,
                              hipFuncAttributeMaxDynamicSharedMemorySize, LSA_LDS_BYTES);

    front_kernel<<<BB * NPART, 128, FRONT_LDS_BYTES, stream>>>(logits, pboxes, gboxes, glabels,
                                                               lse, vidx, nval, cost, fpart);
    lsa_kernel<<<BB, 64, LSA_LDS_BYTES, stream>>>(cost, nval, vidx, glabels, lse, pboxes, gboxes,
                                                  logits, mpart);
    final_kernel<<<1, 64, 0, stream>>>(nval, fpart, mpart, out);
}

// Round 2
// 253.080 us; speedup vs baseline: 1.1468x; 1.1468x over previous
//
#include <hip/hip_runtime.h>
#include <math.h>

#define BB 128
#define QQ 900
#define GG 80
#define CC 92
#define NCL 91
#define NSLOT 15  // ceil(QQ/64)

#define NPART 8   // front: parts per batch
#define QPB 128   // q rows per front block

// ---------------- ws layout (bytes) ---------------- (UNCHANGED)
#define COST_OFF 0            // float[BB*GG*QQ]  36,864,000
#define LSE_OFF  36864000     // float[BB*QQ]
#define VIDX_OFF 37324800     // int[BB*GG]
#define NV_OFF   37365760     // int[BB]
#define FPART_OFF 37366272    // float[BB*NPART=1024] CE-base partials
#define MPART_OFF 37370368    // double[BB*3] lsa matched partials [ce,l1,giou]

#define FRONT_LDS_BYTES (QPB * 93 * 4)   // 47,616 -> 3 blocks/CU

// Fused front kernel v5: same geometry as v4 (grid BB*8, 128 thr, 128 q each),
// same padded-93 LDS layout, same fp32 expression trees (bit-identical cost/lse).
// ONLY change: staging is float4 with 8-deep ILP batches. Round-1 evidence:
// the serial scalar load->ds_write chain (~92 x ~600cy cold-HBM latency per
// thread) dominated front at ~120us regardless of occupancy; 8 loads in
// flight cuts the chain to 3 latencies.
__global__ __launch_bounds__(128) void front_kernel(const float* __restrict__ logits,
                                                    const float* __restrict__ pboxes,
                                                    const float* __restrict__ gboxes,
                                                    const int* __restrict__ glabels,
                                                    float* __restrict__ lse_g,
                                                    int* __restrict__ valid_idx,
                                                    int* __restrict__ nvalid,
                                                    float* __restrict__ cost,
                                                    float* __restrict__ fpart) {
    extern __shared__ float sL[];  // [QPB][93]
    __shared__ int svidx[GG];
    __shared__ int s_n;
    __shared__ int slab[GG];
    __shared__ float sgx0[GG], sgy0[GG], sgx1[GG], sgy1[GG], sgar[GG];
    __shared__ float sgcx[GG], sgcy[GG], sgcz[GG], sgcw[GG];
    __shared__ double sce[2];
    int blk = blockIdx.x;
    int b = blk >> 3;
    int part = blk & 7;
    int tid = threadIdx.x;
    int q0 = part * QPB;
    int qcnt = QQ - q0;
    if (qcnt > QPB) qcnt = QPB;
    if (tid < 64) {
        int lane = tid;
        bool v0 = glabels[b * GG + lane] < NCL;
        bool v1 = (lane < GG - 64) ? (glabels[b * GG + 64 + lane] < NCL) : false;
        unsigned long long m0 = __ballot(v0);
        unsigned long long m1 = __ballot(v1);
        int c0 = __popcll(m0);
        unsigned long long lower = lane ? (~0ULL >> (64 - lane)) : 0ULL;
        if (v0) { int p = __popcll(m0 & lower); svidx[p] = lane; valid_idx[b * GG + p] = lane; }
        if (v1) { int p = c0 + __popcll(m1 & lower); svidx[p] = 64 + lane; valid_idx[b * GG + p] = 64 + lane; }
        if (lane == 0) { s_n = c0 + __popcll(m1); nvalid[b] = s_n; }
    }
    __syncthreads();
    int n = s_n;

    // stage logits slab -> LDS. float4 granularity, 8-deep ILP (loads issued
    // before any dependent ds_write). Layout/values identical to v4:
    // word ql*93 + c, pad word 92 unused.
    {
        const float4* src4 = (const float4*)(logits + ((size_t)b * QQ + q0) * CC);
        int total4 = qcnt * 23;  // 92 floats = 23 float4 per row
        for (int base = 0; base < total4; base += 128 * 8) {
            float4 buf[8];
#pragma unroll
            for (int j = 0; j < 8; ++j) {
                int i = base + j * 128 + tid;
                if (i < total4) buf[j] = src4[i];
            }
#pragma unroll
            for (int j = 0; j < 8; ++j) {
                int i = base + j * 128 + tid;
                if (i < total4) {
                    int ql = i / 23;
                    int c4 = i - ql * 23;
                    float* d = sL + ql * 93 + c4 * 4;
                    d[0] = buf[j].x; d[1] = buf[j].y; d[2] = buf[j].z; d[3] = buf[j].w;
                }
            }
        }
    }
    // gt staging
    for (int k = tid; k < n; k += 128) {
        int g = svidx[k];
        slab[k] = glabels[b * GG + g];
        float4 gb = ((const float4*)gboxes)[b * GG + g];
        sgcx[k] = gb.x; sgcy[k] = gb.y; sgcz[k] = gb.z; sgcw[k] = gb.w;
        float gx0 = gb.x - 0.5f * gb.z, gy0 = gb.y - 0.5f * gb.w;
        float gx1 = gb.x + 0.5f * gb.z, gy1 = gb.y + 0.5f * gb.w;
        sgx0[k] = gx0; sgy0[k] = gy0; sgx1[k] = gx1; sgy1[k] = gy1;
        sgar[k] = (gx1 - gx0) * (gy1 - gy0);
    }
    __syncthreads();

    int q = q0 + tid;
    bool qok = tid < qcnt;
    const float* row = sL + tid * 93;

    // lse (identical expression tree; values from LDS are identical)
    double local = 0.0;
    float lse_q = 0.f;
    if (qok) {
        float mx = -INFINITY;
        for (int c = 0; c < 23; ++c) {
            float x0 = row[4 * c], x1 = row[4 * c + 1], x2 = row[4 * c + 2], x3 = row[4 * c + 3];
            mx = fmaxf(mx, fmaxf(fmaxf(x0, x1), fmaxf(x2, x3)));
        }
        float ssum = 0.f;
        float e91 = 0.f;
        for (int c = 0; c < 23; ++c) {
            float x0 = row[4 * c], x1 = row[4 * c + 1], x2 = row[4 * c + 2], x3 = row[4 * c + 3];
            ssum += expf(x0 - mx) + expf(x1 - mx) + expf(x2 - mx) + expf(x3 - mx);
            if (c == 22) e91 = x3;  // element 91
        }
        lse_q = mx + logf(ssum);
        lse_g[b * QQ + q] = lse_q;
        local = (double)lse_q - (double)e91;
    }
#pragma unroll
    for (int off = 32; off; off >>= 1) local += __shfl_down(local, off);
    if ((tid & 63) == 0) sce[tid >> 6] = local;

    // cost (identical fp32 op order; gather from LDS)
    if (qok) {
        float4 pb = ((const float4*)pboxes)[b * QQ + q];
        float px0 = pb.x - 0.5f * pb.z, py0 = pb.y - 0.5f * pb.w;
        float px1 = pb.x + 0.5f * pb.z, py1 = pb.y + 0.5f * pb.w;
        float parea = (px1 - px0) * (py1 - py0);
        for (int k = 0; k < n; ++k) {
            float l1 = fabsf(pb.x - sgcx[k]) + fabsf(pb.y - sgcy[k]) +
                       fabsf(pb.z - sgcz[k]) + fabsf(pb.w - sgcw[k]);
            float ltx = fmaxf(px0, sgx0[k]), lty = fmaxf(py0, sgy0[k]);
            float rbx = fminf(px1, sgx1[k]), rby = fminf(py1, sgy1[k]);
            float iw = fmaxf(rbx - ltx, 0.f), ih = fmaxf(rby - lty, 0.f);
            float inter = iw * ih;
            float uni = parea + sgar[k] - inter;
            float iou = inter / uni;
            float cx0 = fminf(px0, sgx0[k]), cy0 = fminf(py0, sgy0[k]);
            float cx1 = fmaxf(px1, sgx1[k]), cy1 = fmaxf(py1, sgy1[k]);
            float cw = fmaxf(cx1 - cx0, 0.f), ch = fmaxf(cy1 - cy0, 0.f);
            float ac = cw * ch;
            float giou = iou - (ac - uni) / ac;
            float cls = lse_q - row[slab[k]];
            cost[((size_t)(b * GG + k)) * QQ + q] = 5.f * l1 + cls - 2.f * giou;
        }
    }
    __syncthreads();
    if (tid == 0) fpart[blk] = (float)(sce[0] + sce[1]);
}

// Wave64 min-reduce via DPP (row_shr 1/2/4/8 + bcast15/31), result in lane 63.
__device__ __forceinline__ unsigned wave_min_u32(unsigned x) {
    unsigned t;
    t = (unsigned)__builtin_amdgcn_update_dpp((int)x, (int)x, 0x111, 0xF, 0xF, false); x = x < t ? x : t;
    t = (unsigned)__builtin_amdgcn_update_dpp((int)x, (int)x, 0x112, 0xF, 0xF, false); x = x < t ? x : t;
    t = (unsigned)__builtin_amdgcn_update_dpp((int)x, (int)x, 0x114, 0xF, 0xF, false); x = x < t ? x : t;
    t = (unsigned)__builtin_amdgcn_update_dpp((int)x, (int)x, 0x118, 0xF, 0xF, false); x = x < t ? x : t;
    t = (unsigned)__builtin_amdgcn_update_dpp((int)x, (int)x, 0x142, 0xF, 0xF, false); x = x < t ? x : t;
    t = (unsigned)__builtin_amdgcn_update_dpp((int)x, (int)x, 0x143, 0xF, 0xF, false); x = x < t ? x : t;
    return (unsigned)__builtin_amdgcn_readlane((int)x, 63);
}
// fp32 variant (fminf; values here are never NaN).
__device__ __forceinline__ float wave_min_f32(float x) {
    float t;
#define MSTEP(ctrl)                                                                               \
    t = __uint_as_float((unsigned)__builtin_amdgcn_update_dpp(                                    \
        (int)__float_as_uint(x), (int)__float_as_uint(x), ctrl, 0xF, 0xF, false));                \
    x = fminf(x, t);
    MSTEP(0x111) MSTEP(0x112) MSTEP(0x114) MSTEP(0x118) MSTEP(0x142) MSTEP(0x143)
#undef MSTEP
    return __uint_as_float((unsigned)__builtin_amdgcn_readlane((int)__float_as_uint(x), 63));
}

// One exact SAP phase (scipy semantics) for row `cur`.
// Bit-for-bit the R10-proven dataflow; global fp32 cost rows.
// (Round-1 LDS row-cache REVERTED: preload's serial load->ds_write chain cost
// +42us while the steady-state LDS-vs-L2 latency delta measured ~= 0.)
__device__ __forceinline__ bool sap_phase(int cur, int lane, const float* cbase,
                                          unsigned valid_mask, float (&v)[NSLOT],
                                          int (&r4c_r)[NSLOT], float (&u_r)[2],
                                          int (&c4r_r)[2]) {
    float sh[NSLOT];
    int path_r[NSLOT];
    float srv_r[2] = {0.f, 0.f};
    unsigned sc = 0, srm = 0;
#pragma unroll
    for (int s = 0; s < NSLOT; ++s) sh[s] = INFINITY;
    int i2 = cur;
    float minv = 0.f;
    int sink = -1;
    for (int pop = 0; pop < QQ && sink < 0; ++pop) {
        float uv = (i2 >> 6) ? u_r[1] : u_r[0];
        float ui = __uint_as_float(
            (unsigned)__builtin_amdgcn_readlane((int)__float_as_uint(uv), i2 & 63));
        const float* crow = cbase + (size_t)i2 * QQ;
        float cv[NSLOT];
#pragma unroll
        for (int s = 0; s < NSLOT; ++s) {
            int j = s * 64 + lane;
            cv[s] = (j < QQ) ? crow[j] : 0.f;
        }
        float base = minv - ui;
        unsigned act = valid_mask & ~sc;
        float lmin = INFINITY;
        int lslot = 0;
#pragma unroll
        for (int s = 0; s < NSLOT; ++s) {
            if ((act >> s) & 1u) {
                float r = base + cv[s] - v[s];
                if (r < sh[s]) { sh[s] = r; path_r[s] = i2; }
                if (sh[s] < lmin) { lmin = sh[s]; lslot = s; }
            }
        }
        float gmin = wave_min_f32(lmin);
        unsigned cand = (lmin == gmin) ? (unsigned)(lslot * 64 + lane) : 0xFFFFFFFFu;
        int lj = (int)wave_min_u32(cand);  // lowest column among ties
        minv = gmin;
        if (lane == (lj & 63)) sc |= (1u << (lj >> 6));
        int rv = -1;
#pragma unroll
        for (int s = 0; s < NSLOT; ++s)
            if (s == (lj >> 6)) rv = r4c_r[s];
        int r4c = __builtin_amdgcn_readlane(rv, lj & 63);
        if (r4c == -1) {
            sink = lj;
        } else {
            i2 = r4c;
            if (lane == (i2 & 63)) {
#pragma unroll
                for (int s = 0; s < 2; ++s)
                    if (s == (i2 >> 6)) { srm |= (1u << s); srv_r[s] = minv; }
            }
        }
    }
    if (sink < 0) return false;
    // dual updates (reference order: before augmentation)
    if (lane == (cur & 63)) {
#pragma unroll
        for (int s = 0; s < 2; ++s)
            if (s == (cur >> 6)) u_r[s] += minv;
    }
#pragma unroll
    for (int s = 0; s < 2; ++s)
        if ((srm >> s) & 1u) u_r[s] += minv - srv_r[s];
#pragma unroll
    for (int s = 0; s < NSLOT; ++s)
        if ((sc >> s) & 1u) v[s] -= (minv - sh[s]);
    // augment (wave-cooperative, uniform walk)
    int j = sink;
    while (true) {
        int pslot = j >> 6, plane = j & 63;
        int pv = 0;
#pragma unroll
        for (int s = 0; s < NSLOT; ++s)
            if (s == pslot) pv = path_r[s];
        int pi = __builtin_amdgcn_readlane(pv, plane);
        if (lane == plane) {
#pragma unroll
            for (int s = 0; s < NSLOT; ++s)
                if (s == pslot) r4c_r[s] = pi;
        }
        int cslot = pi >> 6, clane = pi & 63;
        int cvv = 0;
#pragma unroll
        for (int s = 0; s < 2; ++s)
            if (s == cslot) cvv = c4r_r[s];
        int nj = __builtin_amdgcn_readlane(cvv, clane);
        if (lane == clane) {
#pragma unroll
            for (int s = 0; s < 2; ++s)
                if (s == cslot) c4r_r[s] = j;
        }
        j = nj;
        if (pi == cur) break;
    }
    return true;
}

// R10-proven exact LSA: v=0 init, sequential SAP rows 0..n-1 (scipy traversal).
// One 64-lane wave per batch, all state in registers. (Round-0 version, verbatim.)
__global__ __launch_bounds__(64, 1) void lsa_kernel(const float* __restrict__ cost,
                                                    const int* __restrict__ nvalid,
                                                    const int* __restrict__ valid_idx,
                                                    const int* __restrict__ glabels,
                                                    const float* __restrict__ lse_g,
                                                    const float* __restrict__ pboxes,
                                                    const float* __restrict__ gboxes,
                                                    const float* __restrict__ logits,
                                                    double* __restrict__ mpart) {
    int b = blockIdx.x;
    int n = nvalid[b];
    const float* cbase = cost + (size_t)b * GG * QQ;
    int lane = threadIdx.x;

    float v[NSLOT];
    int r4c_r[NSLOT];
    float u_r[2];
    int c4r_r[2];
    unsigned valid_mask = 0x3FFFu | ((lane < QQ - 14 * 64) ? 0x4000u : 0u);
#pragma unroll
    for (int s = 0; s < NSLOT; ++s) { v[s] = 0.f; r4c_r[s] = -1; }
#pragma unroll
    for (int s = 0; s < 2; ++s) { u_r[s] = 0.f; c4r_r[s] = -1; }

    for (int cur = 0; cur < n; ++cur)
        sap_phase(cur, lane, cbase, valid_mask, v, r4c_r, u_r, c4r_r);

    // ---- fused matched-pair losses ----
    double ce = 0.0, dl1 = 0.0, dgi = 0.0;
#pragma unroll
    for (int s = 0; s < 2; ++s) {
        int r = s * 64 + lane;
        int q = c4r_r[s];
        if (r < n && q >= 0 && q < QQ) {
            int g = valid_idx[b * GG + r];
            int label = glabels[b * GG + g];
            if (label < 0 || label >= CC) label = 0;
            size_t ro = ((size_t)b * QQ + q) * CC;
            float ls = lse_g[b * QQ + q];
            float nll_lab = ls - logits[ro + label];
            float nll_no = ls - logits[ro + NCL];
            ce += 0.1 * (double)nll_lab - (double)nll_no;
            float4 pb = ((const float4*)pboxes)[b * QQ + q];
            float4 gb = ((const float4*)gboxes)[b * GG + g];
            float l1 = fabsf(pb.x - gb.x) + fabsf(pb.y - gb.y) + fabsf(pb.z - gb.z) + fabsf(pb.w - gb.w);
            float px0 = pb.x - 0.5f * pb.z, py0 = pb.y - 0.5f * pb.w;
            float px1 = pb.x + 0.5f * pb.z, py1 = pb.y + 0.5f * pb.w;
            float gx0 = gb.x - 0.5f * gb.z, gy0 = gb.y - 0.5f * gb.w;
            float gx1 = gb.x + 0.5f * gb.z, gy1 = gb.y + 0.5f * gb.w;
            float parea = (px1 - px0) * (py1 - py0);
            float garea = (gx1 - gx0) * (gy1 - gy0);
            float ltx = fmaxf(px0, gx0), lty = fmaxf(py0, gy0);
            float rbx = fminf(px1, gx1), rby = fminf(py1, gy1);
            float iw = fmaxf(rbx - ltx, 0.f), ih = fmaxf(rby - lty, 0.f);
            float inter = iw * ih;
            float uni = parea + garea - inter;
            float iou = inter / uni;
            float cx0 = fminf(px0, gx0), cy0 = fminf(py0, gy0);
            float cx1 = fmaxf(px1, gx1), cy1 = fmaxf(py1, gy1);
            float cw = fmaxf(cx1 - cx0, 0.f), ch = fmaxf(cy1 - cy0, 0.f);
            float ac = cw * ch;
            float giou = iou - (ac - uni) / ac;
            dl1 += (double)l1;
            dgi += 1.0 - (double)giou;
        }
    }
#pragma unroll
    for (int off = 32; off; off >>= 1) {
        ce += __shfl_down(ce, off);
        dl1 += __shfl_down(dl1, off);
        dgi += __shfl_down(dgi, off);
    }
    if (lane == 0) {
        mpart[b * 3 + 0] = ce;
        mpart[b * 3 + 1] = dl1;
        mpart[b * 3 + 2] = dgi;
    }
}

// One wave: sum partials + nvalid -> the three losses (no atomics anywhere).
__global__ __launch_bounds__(64) void final_kernel(const int* __restrict__ nvalid,
                                                   const float* __restrict__ fpart,
                                                   const double* __restrict__ mpart,
                                                   float* __restrict__ out) {
    int lane = threadIdx.x;
    int m = nvalid[lane] + nvalid[64 + lane];  // BB = 128
    double fb = 0.0;
    for (int i = lane; i < BB * NPART; i += 64) fb += (double)fpart[i];
    double ce = 0.0, dl1 = 0.0, dgi = 0.0;
#pragma unroll
    for (int s = 0; s < 2; ++s) {
        int bb = s * 64 + lane;
        ce += mpart[bb * 3 + 0];
        dl1 += mpart[bb * 3 + 1];
        dgi += mpart[bb * 3 + 2];
    }
#pragma unroll
    for (int off = 32; off; off >>= 1) {
        m += __shfl_down(m, off);
        fb += __shfl_down(fb, off);
        ce += __shfl_down(ce, off);
        dl1 += __shfl_down(dl1, off);
        dgi += __shfl_down(dgi, off);
    }
    if (lane == 0) {
        double M = (double)m;
        double sum_w = (double)(BB * QQ) - 0.9 * M;
        out[0] = (float)((fb + ce) / sum_w);
        out[1] = (float)(dl1 / (4.0 * M));
        out[2] = (float)(dgi / M);
    }
}

extern "C" void kernel_launch(void* const* d_in, const int* in_sizes, int n_in,
                              void* d_out, int out_size, void* d_ws, size_t ws_size,
                              hipStream_t stream) {
    const float* logits = (const float*)d_in[0];
    const float* pboxes = (const float*)d_in[1];
    const int* glabels = (const int*)d_in[2];
    const float* gboxes = (const float*)d_in[3];
    float* out = (float*)d_out;

    char* ws = (char*)d_ws;
    float* cost = (float*)(ws + COST_OFF);
    float* lse = (float*)(ws + LSE_OFF);
    int* vidx = (int*)(ws + VIDX_OFF);
    int* nval = (int*)(ws + NV_OFF);
    float* fpart = (float*)(ws + FPART_OFF);
    double* mpart = (double*)(ws + MPART_OFF);

    (void)hipFuncSetAttribute((const void*)front_kernel,
                              hipFuncAttributeMaxDynamicSharedMemorySize, FRONT_LDS_BYTES);

    front_kernel<<<BB * NPART, 128, FRONT_LDS_BYTES, stream>>>(logits, pboxes, gboxes, glabels,
                                                               lse, vidx, nval, cost, fpart);
    lsa_kernel<<<BB, 64, 0, stream>>>(cost, nval, vidx, glabels, lse, pboxes, gboxes, logits, mpart);
    final_kernel<<<1, 64, 0, stream>>>(nval, fpart, mpart, out);
}

// Round 4
// 223.311 us; speedup vs baseline: 1.2997x; 1.1333x over previous
//
#include <hip/hip_runtime.h>
#include <math.h>

#define BB 128
#define QQ 900
#define GG 80
#define CC 92
#define NCL 91
#define NSLOT 15  // ceil(QQ/64)

#define NPART 8   // front: parts per batch
#define QPB 128   // q rows per front block

// ---------------- ws layout (bytes) ---------------- (UNCHANGED)
#define COST_OFF 0            // float[BB*GG*QQ]  36,864,000
#define LSE_OFF  36864000     // float[BB*QQ]
#define VIDX_OFF 37324800     // int[BB*GG]
#define NV_OFF   37365760     // int[BB]
#define FPART_OFF 37366272    // float[BB*NPART=1024] CE-base partials
#define MPART_OFF 37370368    // double[BB*3] lsa matched partials [ce,l1,giou]

#define FRONT_LDS_BYTES (QPB * 93 * 4)   // 47,616 -> 3 blocks/CU

// Fused front kernel (r1 form, verbatim): grid BB*8, 128 thr, 128 q each,
// padded-93 LDS layout, bit-identical fp32 expression trees. r2's predicated
// ILP staging batches cost +5us and are reverted; r0/r1/r2 showed front's
// residual (total - lsa - final) is ~constant ~122us across radically
// different front structures => front itself is small (~15us) and the
// residual is dominated by per-iteration harness overhead we don't control.
__global__ __launch_bounds__(128) void front_kernel(const float* __restrict__ logits,
                                                    const float* __restrict__ pboxes,
                                                    const float* __restrict__ gboxes,
                                                    const int* __restrict__ glabels,
                                                    float* __restrict__ lse_g,
                                                    int* __restrict__ valid_idx,
                                                    int* __restrict__ nvalid,
                                                    float* __restrict__ cost,
                                                    float* __restrict__ fpart) {
    extern __shared__ float sL[];  // [QPB][93]
    __shared__ int svidx[GG];
    __shared__ int s_n;
    __shared__ int slab[GG];
    __shared__ float sgx0[GG], sgy0[GG], sgx1[GG], sgy1[GG], sgar[GG];
    __shared__ float sgcx[GG], sgcy[GG], sgcz[GG], sgcw[GG];
    __shared__ double sce[2];
    int blk = blockIdx.x;
    int b = blk >> 3;
    int part = blk & 7;
    int tid = threadIdx.x;
    int q0 = part * QPB;
    int qcnt = QQ - q0;
    if (qcnt > QPB) qcnt = QPB;
    if (tid < 64) {
        int lane = tid;
        bool v0 = glabels[b * GG + lane] < NCL;
        bool v1 = (lane < GG - 64) ? (glabels[b * GG + 64 + lane] < NCL) : false;
        unsigned long long m0 = __ballot(v0);
        unsigned long long m1 = __ballot(v1);
        int c0 = __popcll(m0);
        unsigned long long lower = lane ? (~0ULL >> (64 - lane)) : 0ULL;
        if (v0) { int p = __popcll(m0 & lower); svidx[p] = lane; valid_idx[b * GG + p] = lane; }
        if (v1) { int p = c0 + __popcll(m1 & lower); svidx[p] = 64 + lane; valid_idx[b * GG + p] = 64 + lane; }
        if (lane == 0) { s_n = c0 + __popcll(m1); nvalid[b] = s_n; }
    }
    __syncthreads();
    int n = s_n;

    // stage logits slab -> LDS (coalesced dword reads; padded stride 93)
    {
        const float* src = logits + ((size_t)b * QQ + q0) * CC;
        for (int i = tid; i < qcnt * CC; i += 128) {
            int ql = i / CC;
            int c = i - ql * CC;
            sL[ql * 93 + c] = src[i];
        }
    }
    // gt staging
    for (int k = tid; k < n; k += 128) {
        int g = svidx[k];
        slab[k] = glabels[b * GG + g];
        float4 gb = ((const float4*)gboxes)[b * GG + g];
        sgcx[k] = gb.x; sgcy[k] = gb.y; sgcz[k] = gb.z; sgcw[k] = gb.w;
        float gx0 = gb.x - 0.5f * gb.z, gy0 = gb.y - 0.5f * gb.w;
        float gx1 = gb.x + 0.5f * gb.z, gy1 = gb.y + 0.5f * gb.w;
        sgx0[k] = gx0; sgy0[k] = gy0; sgx1[k] = gx1; sgy1[k] = gy1;
        sgar[k] = (gx1 - gx0) * (gy1 - gy0);
    }
    __syncthreads();

    int q = q0 + tid;
    bool qok = tid < qcnt;
    const float* row = sL + tid * 93;

    // lse (identical expression tree; values from LDS are identical)
    double local = 0.0;
    float lse_q = 0.f;
    if (qok) {
        float mx = -INFINITY;
        for (int c = 0; c < 23; ++c) {
            float x0 = row[4 * c], x1 = row[4 * c + 1], x2 = row[4 * c + 2], x3 = row[4 * c + 3];
            mx = fmaxf(mx, fmaxf(fmaxf(x0, x1), fmaxf(x2, x3)));
        }
        float ssum = 0.f;
        float e91 = 0.f;
        for (int c = 0; c < 23; ++c) {
            float x0 = row[4 * c], x1 = row[4 * c + 1], x2 = row[4 * c + 2], x3 = row[4 * c + 3];
            ssum += expf(x0 - mx) + expf(x1 - mx) + expf(x2 - mx) + expf(x3 - mx);
            if (c == 22) e91 = x3;  // element 91
        }
        lse_q = mx + logf(ssum);
        lse_g[b * QQ + q] = lse_q;
        local = (double)lse_q - (double)e91;
    }
#pragma unroll
    for (int off = 32; off; off >>= 1) local += __shfl_down(local, off);
    if ((tid & 63) == 0) sce[tid >> 6] = local;

    // cost (identical fp32 op order; gather from LDS)
    if (qok) {
        float4 pb = ((const float4*)pboxes)[b * QQ + q];
        float px0 = pb.x - 0.5f * pb.z, py0 = pb.y - 0.5f * pb.w;
        float px1 = pb.x + 0.5f * pb.z, py1 = pb.y + 0.5f * pb.w;
        float parea = (px1 - px0) * (py1 - py0);
        for (int k = 0; k < n; ++k) {
            float l1 = fabsf(pb.x - sgcx[k]) + fabsf(pb.y - sgcy[k]) +
                       fabsf(pb.z - sgcz[k]) + fabsf(pb.w - sgcw[k]);
            float ltx = fmaxf(px0, sgx0[k]), lty = fmaxf(py0, sgy0[k]);
            float rbx = fminf(px1, sgx1[k]), rby = fminf(py1, sgy1[k]);
            float iw = fmaxf(rbx - ltx, 0.f), ih = fmaxf(rby - lty, 0.f);
            float inter = iw * ih;
            float uni = parea + sgar[k] - inter;
            float iou = inter / uni;
            float cx0 = fminf(px0, sgx0[k]), cy0 = fminf(py0, sgy0[k]);
            float cx1 = fmaxf(px1, sgx1[k]), cy1 = fmaxf(py1, sgy1[k]);
            float cw = fmaxf(cx1 - cx0, 0.f), ch = fmaxf(cy1 - cy0, 0.f);
            float ac = cw * ch;
            float giou = iou - (ac - uni) / ac;
            float cls = lse_q - row[slab[k]];
            cost[((size_t)(b * GG + k)) * QQ + q] = 5.f * l1 + cls - 2.f * giou;
        }
    }
    __syncthreads();
    if (tid == 0) fpart[blk] = (float)(sce[0] + sce[1]);
}

// Wave64 min-reduce via DPP (row_shr 1/2/4/8 + bcast15/31), result in lane 63.
__device__ __forceinline__ unsigned wave_min_u32(unsigned x) {
    unsigned t;
    t = (unsigned)__builtin_amdgcn_update_dpp((int)x, (int)x, 0x111, 0xF, 0xF, false); x = x < t ? x : t;
    t = (unsigned)__builtin_amdgcn_update_dpp((int)x, (int)x, 0x112, 0xF, 0xF, false); x = x < t ? x : t;
    t = (unsigned)__builtin_amdgcn_update_dpp((int)x, (int)x, 0x114, 0xF, 0xF, false); x = x < t ? x : t;
    t = (unsigned)__builtin_amdgcn_update_dpp((int)x, (int)x, 0x118, 0xF, 0xF, false); x = x < t ? x : t;
    t = (unsigned)__builtin_amdgcn_update_dpp((int)x, (int)x, 0x142, 0xF, 0xF, false); x = x < t ? x : t;
    t = (unsigned)__builtin_amdgcn_update_dpp((int)x, (int)x, 0x143, 0xF, 0xF, false); x = x < t ? x : t;
    return (unsigned)__builtin_amdgcn_readlane((int)x, 63);
}
// fp32 variant (fminf; values here are never NaN).
__device__ __forceinline__ float wave_min_f32(float x) {
    float t;
#define MSTEP(ctrl)                                                                               \
    t = __uint_as_float((unsigned)__builtin_amdgcn_update_dpp(                                    \
        (int)__float_as_uint(x), (int)__float_as_uint(x), ctrl, 0xF, 0xF, false));                \
    x = fminf(x, t);
    MSTEP(0x111) MSTEP(0x112) MSTEP(0x114) MSTEP(0x118) MSTEP(0x142) MSTEP(0x143)
#undef MSTEP
    return __uint_as_float((unsigned)__builtin_amdgcn_readlane((int)__float_as_uint(x), 63));
}

// One exact SAP phase (scipy semantics) for row `cur`.
// Bit-for-bit the R10-proven dataflow. NEW (bit-exact by construction):
// pop 0 always reads row==cur (cur is unmatched, so the alternating path
// cannot point back to it mid-phase) -- its 15 column loads are supplied via
// the prefetch registers pf[], filled during the PREVIOUS phase's dual-update
// + augment readlane chain. Same addresses, same bits, just issued ~400cy
// earlier, removing the first-pop L2 latency from every phase's critical path.
__device__ __forceinline__ bool sap_phase(int cur, int lane, const float* cbase,
                                          unsigned valid_mask, float (&v)[NSLOT],
                                          int (&r4c_r)[NSLOT], float (&u_r)[2],
                                          int (&c4r_r)[2], float (&pf)[NSLOT], int nrows) {
    float sh[NSLOT];
    int path_r[NSLOT];
    float srv_r[2] = {0.f, 0.f};
    unsigned sc = 0, srm = 0;
#pragma unroll
    for (int s = 0; s < NSLOT; ++s) sh[s] = INFINITY;
    int i2 = cur;
    float minv = 0.f;
    int sink = -1;
    for (int pop = 0; pop < QQ && sink < 0; ++pop) {
        float cv[NSLOT];
        if (pop == 0) {
#pragma unroll
            for (int s = 0; s < NSLOT; ++s) cv[s] = pf[s];
        } else {
            const float* crow = cbase + (size_t)i2 * QQ;
#pragma unroll
            for (int s = 0; s < NSLOT; ++s) {
                int j = s * 64 + lane;
                cv[s] = (j < QQ) ? crow[j] : 0.f;
            }
        }
        float uv = (i2 >> 6) ? u_r[1] : u_r[0];
        float ui = __uint_as_float(
            (unsigned)__builtin_amdgcn_readlane((int)__float_as_uint(uv), i2 & 63));
        float base = minv - ui;
        unsigned act = valid_mask & ~sc;
        float lmin = INFINITY;
        int lslot = 0;
#pragma unroll
        for (int s = 0; s < NSLOT; ++s) {
            if ((act >> s) & 1u) {
                float r = base + cv[s] - v[s];
                if (r < sh[s]) { sh[s] = r; path_r[s] = i2; }
                if (sh[s] < lmin) { lmin = sh[s]; lslot = s; }
            }
        }
        float gmin = wave_min_f32(lmin);
        unsigned cand = (lmin == gmin) ? (unsigned)(lslot * 64 + lane) : 0xFFFFFFFFu;
        int lj = (int)wave_min_u32(cand);  // lowest column among ties
        minv = gmin;
        if (lane == (lj & 63)) sc |= (1u << (lj >> 6));
        int rv = -1;
#pragma unroll
        for (int s = 0; s < NSLOT; ++s)
            if (s == (lj >> 6)) rv = r4c_r[s];
        int r4c = __builtin_amdgcn_readlane(rv, lj & 63);
        if (r4c == -1) {
            sink = lj;
        } else {
            i2 = r4c;
            if (lane == (i2 & 63)) {
#pragma unroll
                for (int s = 0; s < 2; ++s)
                    if (s == (i2 >> 6)) { srm |= (1u << s); srv_r[s] = minv; }
            }
        }
    }
    if (sink < 0) return false;
    // prefetch next phase's pop-0 row (row cur+1) -- flies under the
    // dual-update + augment readlane chains below
    {
        int nxt = cur + 1;
        if (nxt < nrows) {
            const float* nrow = cbase + (size_t)nxt * QQ;
#pragma unroll
            for (int s = 0; s < NSLOT; ++s) {
                int j = s * 64 + lane;
                pf[s] = (j < QQ) ? nrow[j] : 0.f;
            }
        }
    }
    // dual updates (reference order: before augmentation)
    if (lane == (cur & 63)) {
#pragma unroll
        for (int s = 0; s < 2; ++s)
            if (s == (cur >> 6)) u_r[s] += minv;
    }
#pragma unroll
    for (int s = 0; s < 2; ++s)
        if ((srm >> s) & 1u) u_r[s] += minv - srv_r[s];
#pragma unroll
    for (int s = 0; s < NSLOT; ++s)
        if ((sc >> s) & 1u) v[s] -= (minv - sh[s]);
    // augment (wave-cooperative, uniform walk)
    int j = sink;
    while (true) {
        int pslot = j >> 6, plane = j & 63;
        int pv = 0;
#pragma unroll
        for (int s = 0; s < NSLOT; ++s)
            if (s == pslot) pv = path_r[s];
        int pi = __builtin_amdgcn_readlane(pv, plane);
        if (lane == plane) {
#pragma unroll
            for (int s = 0; s < NSLOT; ++s)
                if (s == pslot) r4c_r[s] = pi;
        }
        int cslot = pi >> 6, clane = pi & 63;
        int cvv = 0;
#pragma unroll
        for (int s = 0; s < 2; ++s)
            if (s == cslot) cvv = c4r_r[s];
        int nj = __builtin_amdgcn_readlane(cvv, clane);
        if (lane == clane) {
#pragma unroll
            for (int s = 0; s < 2; ++s)
                if (s == cslot) c4r_r[s] = j;
        }
        j = nj;
        if (pi == cur) break;
    }
    return true;
}

// R10-proven exact LSA: v=0 init, sequential SAP rows 0..n-1 (scipy traversal).
// One 64-lane wave per batch, all state in registers. + cross-phase prefetch.
__global__ __launch_bounds__(64, 1) void lsa_kernel(const float* __restrict__ cost,
                                                    const int* __restrict__ nvalid,
                                                    const int* __restrict__ valid_idx,
                                                    const int* __restrict__ glabels,
                                                    const float* __restrict__ lse_g,
                                                    const float* __restrict__ pboxes,
                                                    const float* __restrict__ gboxes,
                                                    const float* __restrict__ logits,
                                                    double* __restrict__ mpart) {
    int b = blockIdx.x;
    int n = nvalid[b];
    const float* cbase = cost + (size_t)b * GG * QQ;
    int lane = threadIdx.x;

    float v[NSLOT];
    int r4c_r[NSLOT];
    float u_r[2];
    int c4r_r[2];
    float pf[NSLOT];
    unsigned valid_mask = 0x3FFFu | ((lane < QQ - 14 * 64) ? 0x4000u : 0u);
#pragma unroll
    for (int s = 0; s < NSLOT; ++s) { v[s] = 0.f; r4c_r[s] = -1; pf[s] = 0.f; }
#pragma unroll
    for (int s = 0; s < 2; ++s) { u_r[s] = 0.f; c4r_r[s] = -1; }

    if (n > 0) {  // prime prefetch with row 0
#pragma unroll
        for (int s = 0; s < NSLOT; ++s) {
            int j = s * 64 + lane;
            pf[s] = (j < QQ) ? cbase[j] : 0.f;
        }
    }
    for (int cur = 0; cur < n; ++cur)
        sap_phase(cur, lane, cbase, valid_mask, v, r4c_r, u_r, c4r_r, pf, n);

    // ---- fused matched-pair losses ----
    double ce = 0.0, dl1 = 0.0, dgi = 0.0;
#pragma unroll
    for (int s = 0; s < 2; ++s) {
        int r = s * 64 + lane;
        int q = c4r_r[s];
        if (r < n && q >= 0 && q < QQ) {
            int g = valid_idx[b * GG + r];
            int label = glabels[b * GG + g];
            if (label < 0 || label >= CC) label = 0;
            size_t ro = ((size_t)b * QQ + q) * CC;
            float ls = lse_g[b * QQ + q];
            float nll_lab = ls - logits[ro + label];
            float nll_no = ls - logits[ro + NCL];
            ce += 0.1 * (double)nll_lab - (double)nll_no;
            float4 pb = ((const float4*)pboxes)[b * QQ + q];
            float4 gb = ((const float4*)gboxes)[b * GG + g];
            float l1 = fabsf(pb.x - gb.x) + fabsf(pb.y - gb.y) + fabsf(pb.z - gb.z) + fabsf(pb.w - gb.w);
            float px0 = pb.x - 0.5f * pb.z, py0 = pb.y - 0.5f * pb.w;
            float px1 = pb.x + 0.5f * pb.z, py1 = pb.y + 0.5f * pb.w;
            float gx0 = gb.x - 0.5f * gb.z, gy0 = gb.y - 0.5f * gb.w;
            float gx1 = gb.x + 0.5f * gb.z, gy1 = gb.y + 0.5f * gb.w;
            float parea = (px1 - px0) * (py1 - py0);
            float garea = (gx1 - gx0) * (gy1 - gy0);
            float ltx = fmaxf(px0, gx0), lty = fmaxf(py0, gy0);
            float rbx = fminf(px1, gx1), rby = fminf(py1, gy1);
            float iw = fmaxf(rbx - ltx, 0.f), ih = fmaxf(rby - lty, 0.f);
            float inter = iw * ih;
            float uni = parea + garea - inter;
            float iou = inter / uni;
            float cx0 = fminf(px0, gx0), cy0 = fminf(py0, gy0);
            float cx1 = fmaxf(px1, gx1), cy1 = fmaxf(py1, gy1);
            float cw = fmaxf(cx1 - cx0, 0.f), ch = fmaxf(cy1 - cy0, 0.f);
            float ac = cw * ch;
            float giou = iou - (ac - uni) / ac;
            dl1 += (double)l1;
            dgi += 1.0 - (double)giou;
        }
    }
#pragma unroll
    for (int off = 32; off; off >>= 1) {
        ce += __shfl_down(ce, off);
        dl1 += __shfl_down(dl1, off);
        dgi += __shfl_down(dgi, off);
    }
    if (lane == 0) {
        mpart[b * 3 + 0] = ce;
        mpart[b * 3 + 1] = dl1;
        mpart[b * 3 + 2] = dgi;
    }
}

// One wave: sum partials + nvalid -> the three losses (no atomics anywhere).
__global__ __launch_bounds__(64) void final_kernel(const int* __restrict__ nvalid,
                                                   const float* __restrict__ fpart,
                                                   const double* __restrict__ mpart,
                                                   float* __restrict__ out) {
    int lane = threadIdx.x;
    int m = nvalid[lane] + nvalid[64 + lane];  // BB = 128
    double fb = 0.0;
    for (int i = lane; i < BB * NPART; i += 64) fb += (double)fpart[i];
    double ce = 0.0, dl1 = 0.0, dgi = 0.0;
#pragma unroll
    for (int s = 0; s < 2; ++s) {
        int bb = s * 64 + lane;
        ce += mpart[bb * 3 + 0];
        dl1 += mpart[bb * 3 + 1];
        dgi += mpart[bb * 3 + 2];
    }
#pragma unroll
    for (int off = 32; off; off >>= 1) {
        m += __shfl_down(m, off);
        fb += __shfl_down(fb, off);
        ce += __shfl_down(ce, off);
        dl1 += __shfl_down(dl1, off);
        dgi += __shfl_down(dgi, off);
    }
    if (lane == 0) {
        double M = (double)m;
        double sum_w = (double)(BB * QQ) - 0.9 * M;
        out[0] = (float)((fb + ce) / sum_w);
        out[1] = (float)(dl1 / (4.0 * M));
        out[2] = (float)(dgi / M);
    }
}

extern "C" void kernel_launch(void* const* d_in, const int* in_sizes, int n_in,
                              void* d_out, int out_size, void* d_ws, size_t ws_size,
                              hipStream_t stream) {
    const float* logits = (const float*)d_in[0];
    const float* pboxes = (const float*)d_in[1];
    const int* glabels = (const int*)d_in[2];
    const float* gboxes = (const float*)d_in[3];
    float* out = (float*)d_out;

    char* ws = (char*)d_ws;
    float* cost = (float*)(ws + COST_OFF);
    float* lse = (float*)(ws + LSE_OFF);
    int* vidx = (int*)(ws + VIDX_OFF);
    int* nval = (int*)(ws + NV_OFF);
    float* fpart = (float*)(ws + FPART_OFF);
    double* mpart = (double*)(ws + MPART_OFF);

    (void)hipFuncSetAttribute((const void*)front_kernel,
                              hipFuncAttributeMaxDynamicSharedMemorySize, FRONT_LDS_BYTES);

    front_kernel<<<BB * NPART, 128, FRONT_LDS_BYTES, stream>>>(logits, pboxes, gboxes, glabels,
                                                               lse, vidx, nval, cost, fpart);
    lsa_kernel<<<BB, 64, 0, stream>>>(cost, nval, vidx, glabels, lse, pboxes, gboxes, logits, mpart);
    final_kernel<<<1, 64, 0, stream>>>(nval, fpart, mpart, out);
}